// Round 2
// baseline (416.470 us; speedup 1.0000x reference)
//
#include <hip/hip_runtime.h>
#include <hip/hip_bf16.h>

#define N_GAUSS 4096
#define H 512
#define W 512
#define HW (H * W)

// ---------------- workspace layout (floats) ----------------
// cx      [4096]  @ 0
// cy      [4096]  @ 4096
// dz      [4096]  @ 8192      (pos_cam z, the stored depth value)
// key     [4096]  @ 12288     (-proj_z, the sort key)
// sorted  [4096*8]@ 20480     (AoS: float4 {cx,cy,dz,op}, float4 {r,g,b,0})

__global__ void proj_kernel(const float* __restrict__ pos,
                            const float* __restrict__ quat,
                            const float* __restrict__ cam,
                            const float* __restrict__ K,
                            float* __restrict__ cx, float* __restrict__ cy,
                            float* __restrict__ dz, float* __restrict__ key) {
    int i = blockIdx.x * blockDim.x + threadIdx.x;
    if (i >= N_GAUSS) return;
    float qw = quat[0], qx = quat[1], qy = quat[2], qz = quat[3];
    float qn = 1.0f / sqrtf(qw * qw + qx * qx + qy * qy + qz * qz);
    qw *= qn; qx *= qn; qy *= qn; qz *= qn;
    float r00 = 1.f - 2.f * (qy * qy + qz * qz), r01 = 2.f * (qx * qy - qw * qz), r02 = 2.f * (qx * qz + qw * qy);
    float r10 = 2.f * (qx * qy + qw * qz), r11 = 1.f - 2.f * (qx * qx + qz * qz), r12 = 2.f * (qy * qz - qw * qx);
    float r20 = 2.f * (qx * qz - qw * qy), r21 = 2.f * (qy * qz + qw * qx), r22 = 1.f - 2.f * (qx * qx + qy * qy);
    float px = pos[3 * i] - cam[0], py = pos[3 * i + 1] - cam[1], pz = pos[3 * i + 2] - cam[2];
    float X = r00 * px + r01 * py + r02 * pz;
    float Y = r10 * px + r11 * py + r12 * pz;
    float Z = r20 * px + r21 * py + r22 * pz;
    float u = K[0] * X + K[1] * Y + K[2] * Z;
    float v = K[3] * X + K[4] * Y + K[5] * Z;
    float w = K[6] * X + K[7] * Y + K[8] * Z;
    cx[i] = u / w;
    cy[i] = v / w;
    dz[i] = Z;
    key[i] = -w;
}

// One block, 1024 threads: bitonic sort of 4096 (key ascending = depth descending),
// then gather the sorted AoS.
__global__ __launch_bounds__(1024) void sort_gather_kernel(
        const float* __restrict__ keyg, const float* __restrict__ cx,
        const float* __restrict__ cy, const float* __restrict__ dz,
        const float* __restrict__ colors, const float* __restrict__ opac,
        float4* __restrict__ out) {
    __shared__ float skey[N_GAUSS];
    __shared__ int sidx[N_GAUSS];
    int t = threadIdx.x;
    for (int i = t; i < N_GAUSS; i += 1024) { skey[i] = keyg[i]; sidx[i] = i; }
    __syncthreads();
    for (int k = 2; k <= N_GAUSS; k <<= 1) {
        for (int j = k >> 1; j > 0; j >>= 1) {
            for (int i = t; i < N_GAUSS; i += 1024) {
                int ixj = i ^ j;
                if (ixj > i) {
                    bool up = ((i & k) == 0);
                    float a = skey[i], b = skey[ixj];
                    if ((a > b) == up) {
                        skey[i] = b; skey[ixj] = a;
                        int ti = sidx[i]; sidx[i] = sidx[ixj]; sidx[ixj] = ti;
                    }
                }
            }
            __syncthreads();
        }
    }
    for (int g = t; g < N_GAUSS; g += 1024) {
        int id = sidx[g];
        out[2 * g]     = make_float4(cx[id], cy[id], dz[id], opac[id]);
        out[2 * g + 1] = make_float4(colors[3 * id], colors[3 * id + 1], colors[3 * id + 2], 0.f);
    }
}

#define CHUNK 256
#define CULL2 2025.0f   // 45^2: min pixel distance ~34.4 -> alpha <= 2.5e-11

__global__ __launch_bounds__(256) void render_kernel(
        const float4* __restrict__ gs, const float* __restrict__ bg,
        float* __restrict__ out) {
    __shared__ float4 sh[2 * CHUNK];
    int tx = threadIdx.x, ty = threadIdx.y;
    int j = blockIdx.x * 16 + tx;
    int i = blockIdx.y * 16 + ty;
    float px = (float)j, py = (float)i;
    float tcx = blockIdx.x * 16 + 7.5f, tcy = blockIdx.y * 16 + 7.5f;
    float T = 1.f;
    float cr = bg[0], cg = bg[1], cb = bg[2];
    float da = 0.f, aa = 0.f;
    int tid = ty * 16 + tx;
    for (int c0 = 0; c0 < N_GAUSS; c0 += CHUNK) {
        sh[2 * tid]     = gs[2 * (c0 + tid)];
        sh[2 * tid + 1] = gs[2 * (c0 + tid) + 1];
        __syncthreads();
        #pragma unroll 4
        for (int g = 0; g < CHUNK; ++g) {
            float4 A = sh[2 * g];
            float ddx = A.x - tcx, ddy = A.y - tcy;
            if (ddx * ddx + ddy * ddy > CULL2) continue;   // block-uniform cull
            float dx = px - A.x, dy = py - A.y;
            float d2 = dx * dx + dy * dy;
            float al = __expf(-0.02f * d2) * A.w;          // exp(-0.5*d2/25)*op
            al = fminf(al, 1.0f);
            float ta = T * al;
            float4 C = sh[2 * g + 1];
            cr += ta * C.x; cg += ta * C.y; cb += ta * C.z;
            da += ta * A.z; aa += ta;
            T -= ta;                                        // T *= (1-al)
        }
        __syncthreads();
    }
    int pid = i * W + j;
    out[pid]          = cr;
    out[HW + pid]     = cg;
    out[2 * HW + pid] = cb;
    out[3 * HW + pid] = da;
    out[4 * HW + pid] = aa;
}

extern "C" void kernel_launch(void* const* d_in, const int* in_sizes, int n_in,
                              void* d_out, int out_size, void* d_ws, size_t ws_size,
                              hipStream_t stream) {
    const float* positions = (const float*)d_in[0];
    const float* colors    = (const float*)d_in[1];
    const float* opacities = (const float*)d_in[2];
    const float* quat      = (const float*)d_in[3];
    const float* cam       = (const float*)d_in[4];
    const float* intr      = (const float*)d_in[5];
    const float* bg        = (const float*)d_in[6];
    float* out = (float*)d_out;

    float* ws  = (float*)d_ws;
    float* cx  = ws;
    float* cy  = ws + 4096;
    float* dz  = ws + 8192;
    float* key = ws + 12288;
    float4* sorted = (float4*)(ws + 20480);

    proj_kernel<<<dim3(N_GAUSS / 256), dim3(256), 0, stream>>>(
        positions, quat, cam, intr, cx, cy, dz, key);
    sort_gather_kernel<<<dim3(1), dim3(1024), 0, stream>>>(
        key, cx, cy, dz, colors, opacities, sorted);
    render_kernel<<<dim3(W / 16, H / 16), dim3(16, 16), 0, stream>>>(
        sorted, bg, out);
}

// Round 4
// 198.612 us; speedup vs baseline: 2.0969x; 2.0969x over previous
//
#include <hip/hip_runtime.h>
#include <hip/hip_bf16.h>

#define N_GAUSS 4096
#define H 512
#define W 512
#define HW (H * W)

// ---------------- workspace layout (floats) ----------------
// cx      [4096]  @ 0
// cy      [4096]  @ 4096
// dz      [4096]  @ 8192      (pos_cam z, the stored depth value)
// key     [4096]  @ 12288     (-proj_z, the sort key)
// sorted  [4096*8]@ 20480     (AoS: float4 {cx,cy,dz,op}, float4 {r,g,b,0})

__global__ void proj_kernel(const float* __restrict__ pos,
                            const float* __restrict__ quat,
                            const float* __restrict__ cam,
                            const float* __restrict__ K,
                            float* __restrict__ cx, float* __restrict__ cy,
                            float* __restrict__ dz, float* __restrict__ key) {
    int i = blockIdx.x * blockDim.x + threadIdx.x;
    if (i >= N_GAUSS) return;
    float qw = quat[0], qx = quat[1], qy = quat[2], qz = quat[3];
    float qn = 1.0f / sqrtf(qw * qw + qx * qx + qy * qy + qz * qz);
    qw *= qn; qx *= qn; qy *= qn; qz *= qn;
    float r00 = 1.f - 2.f * (qy * qy + qz * qz), r01 = 2.f * (qx * qy - qw * qz), r02 = 2.f * (qx * qz + qw * qy);
    float r10 = 2.f * (qx * qy + qw * qz), r11 = 1.f - 2.f * (qx * qx + qz * qz), r12 = 2.f * (qy * qz - qw * qx);
    float r20 = 2.f * (qx * qz - qw * qy), r21 = 2.f * (qy * qz + qw * qx), r22 = 1.f - 2.f * (qx * qx + qy * qy);
    float px = pos[3 * i] - cam[0], py = pos[3 * i + 1] - cam[1], pz = pos[3 * i + 2] - cam[2];
    float X = r00 * px + r01 * py + r02 * pz;
    float Y = r10 * px + r11 * py + r12 * pz;
    float Z = r20 * px + r21 * py + r22 * pz;
    float u = K[0] * X + K[1] * Y + K[2] * Z;
    float v = K[3] * X + K[4] * Y + K[5] * Z;
    float w = K[6] * X + K[7] * Y + K[8] * Z;
    cx[i] = u / w;
    cy[i] = v / w;
    dz[i] = Z;
    key[i] = -w;
}

// O(N^2) rank sort: 16 blocks x 256 threads. Each thread computes the exact
// rank of one element (stable: index tie-break) against all 4096 keys staged
// in LDS, then scatters the sorted AoS record directly.
__global__ __launch_bounds__(256) void ranksort_kernel(
        const float* __restrict__ keyg, const float* __restrict__ cx,
        const float* __restrict__ cy, const float* __restrict__ dz,
        const float* __restrict__ colors, const float* __restrict__ opac,
        float4* __restrict__ out) {
    __shared__ __align__(16) float sk[N_GAUSS];
    int tid = threadIdx.x;
    for (int i = tid; i < N_GAUSS; i += 256) sk[i] = keyg[i];
    __syncthreads();
    int i = blockIdx.x * 256 + tid;
    float ki = sk[i];
    int r = 0;
    for (int j = 0; j < N_GAUSS; j += 4) {
        float4 k4 = *reinterpret_cast<const float4*>(&sk[j]);   // LDS broadcast
        r += (k4.x < ki) || (k4.x == ki && (j + 0) < i);
        r += (k4.y < ki) || (k4.y == ki && (j + 1) < i);
        r += (k4.z < ki) || (k4.z == ki && (j + 2) < i);
        r += (k4.w < ki) || (k4.w == ki && (j + 3) < i);
    }
    out[2 * r]     = make_float4(cx[i], cy[i], dz[i], opac[i]);
    out[2 * r + 1] = make_float4(colors[3 * i], colors[3 * i + 1], colors[3 * i + 2], 0.f);
}

#define CHUNK 256
#define CULL2 1444.0f   // r=38 from tile center: min pixel dist 26.7 -> skipped alpha <= 6.5e-7

__global__ __launch_bounds__(256) void render_kernel(
        const float4* __restrict__ gs, const float* __restrict__ bg,
        float* __restrict__ out) {
    __shared__ float4 cmp[2 * CHUNK];
    __shared__ unsigned long long wmask[4];
    __shared__ int walive[4];
    int tx = threadIdx.x, ty = threadIdx.y;
    int tid = ty * 16 + tx;
    int lane = tid & 63, wid = tid >> 6;
    int j = blockIdx.x * 16 + tx;
    int i = blockIdx.y * 16 + ty;
    float px = (float)j, py = (float)i;
    float tcx = blockIdx.x * 16 + 7.5f, tcy = blockIdx.y * 16 + 7.5f;
    float T = 1.f;
    float cr = bg[0], cg = bg[1], cb = bg[2];
    float da = 0.f, aa = 0.f;
    for (int c0 = 0; c0 < N_GAUSS; c0 += CHUNK) {
        // load + tile-cull test (one Gaussian per thread, order-preserving compact)
        float4 A = gs[2 * (c0 + tid)];
        float4 C = gs[2 * (c0 + tid) + 1];
        float ddx = A.x - tcx, ddy = A.y - tcy;
        bool pred = (ddx * ddx + ddy * ddy <= CULL2);
        unsigned long long m = __ballot(pred ? 1 : 0);
        unsigned long long am = __ballot(T >= 1e-6f ? 1 : 0);
        if (lane == 0) { wmask[wid] = m; walive[wid] = (am != 0ull); }
        __syncthreads();
        if (!(walive[0] | walive[1] | walive[2] | walive[3])) break;  // all pixels opaque
        unsigned long long m0 = wmask[0], m1 = wmask[1], m2 = wmask[2], m3 = wmask[3];
        int total = __popcll(m0) + __popcll(m1) + __popcll(m2) + __popcll(m3);
        if (pred) {
            int base = 0;
            if (wid > 0) base += __popcll(m0);
            if (wid > 1) base += __popcll(m1);
            if (wid > 2) base += __popcll(m2);
            int pos = base + __popcll(m & ((1ull << lane) - 1ull));
            cmp[2 * pos]     = A;
            cmp[2 * pos + 1] = C;
        }
        __syncthreads();
        for (int g = 0; g < total; ++g) {
            float4 GA = cmp[2 * g];                     // LDS broadcast
            float dx = px - GA.x, dy = py - GA.y;
            float al = __expf(-0.02f * (dx * dx + dy * dy)) * GA.w;  // op<=0.5 -> clip is no-op
            float ta = T * al;
            float4 GC = cmp[2 * g + 1];
            cr += ta * GC.x; cg += ta * GC.y; cb += ta * GC.z;
            da += ta * GA.z; aa += ta;
            T -= ta;                                    // T *= (1-al)
        }
        __syncthreads();
    }
    int pid = i * W + j;
    out[pid]          = cr;
    out[HW + pid]     = cg;
    out[2 * HW + pid] = cb;
    out[3 * HW + pid] = da;
    out[4 * HW + pid] = aa;
}

extern "C" void kernel_launch(void* const* d_in, const int* in_sizes, int n_in,
                              void* d_out, int out_size, void* d_ws, size_t ws_size,
                              hipStream_t stream) {
    const float* positions = (const float*)d_in[0];
    const float* colors    = (const float*)d_in[1];
    const float* opacities = (const float*)d_in[2];
    const float* quat      = (const float*)d_in[3];
    const float* cam       = (const float*)d_in[4];
    const float* intr      = (const float*)d_in[5];
    const float* bg        = (const float*)d_in[6];
    float* out = (float*)d_out;

    float* ws  = (float*)d_ws;
    float* cx  = ws;
    float* cy  = ws + 4096;
    float* dz  = ws + 8192;
    float* key = ws + 12288;
    float4* sorted = (float4*)(ws + 20480);

    proj_kernel<<<dim3(N_GAUSS / 256), dim3(256), 0, stream>>>(
        positions, quat, cam, intr, cx, cy, dz, key);
    ranksort_kernel<<<dim3(N_GAUSS / 256), dim3(256), 0, stream>>>(
        key, cx, cy, dz, colors, opacities, sorted);
    render_kernel<<<dim3(W / 16, H / 16), dim3(16, 16), 0, stream>>>(
        sorted, bg, out);
}

// Round 5
// 116.181 us; speedup vs baseline: 3.5847x; 1.7095x over previous
//
#include <hip/hip_runtime.h>
#include <hip/hip_bf16.h>

#define N_GAUSS 4096
#define H 512
#define W 512
#define HW (H * W)

// ---------------- workspace layout (floats) ----------------
// cx      [4096]  @ 0
// cy      [4096]  @ 4096
// dz      [4096]  @ 8192      (pos_cam z, the stored depth value)
// key     [4096]  @ 12288     (-proj_z, the sort key)
// rank    [4096]  @ 16384     (int, zeroed by proj_kernel)
// sorted  [4096*8]@ 20480     (AoS: float4 {cx,cy,dz,op}, float4 {r,g,b,0})

__global__ void proj_kernel(const float* __restrict__ pos,
                            const float* __restrict__ quat,
                            const float* __restrict__ cam,
                            const float* __restrict__ K,
                            float* __restrict__ cx, float* __restrict__ cy,
                            float* __restrict__ dz, float* __restrict__ key,
                            int* __restrict__ rank) {
    int i = blockIdx.x * blockDim.x + threadIdx.x;
    if (i >= N_GAUSS) return;
    float qw = quat[0], qx = quat[1], qy = quat[2], qz = quat[3];
    float qn = 1.0f / sqrtf(qw * qw + qx * qx + qy * qy + qz * qz);
    qw *= qn; qx *= qn; qy *= qn; qz *= qn;
    float r00 = 1.f - 2.f * (qy * qy + qz * qz), r01 = 2.f * (qx * qy - qw * qz), r02 = 2.f * (qx * qz + qw * qy);
    float r10 = 2.f * (qx * qy + qw * qz), r11 = 1.f - 2.f * (qx * qx + qz * qz), r12 = 2.f * (qy * qz - qw * qx);
    float r20 = 2.f * (qx * qz - qw * qy), r21 = 2.f * (qy * qz + qw * qx), r22 = 1.f - 2.f * (qx * qx + qy * qy);
    float px = pos[3 * i] - cam[0], py = pos[3 * i + 1] - cam[1], pz = pos[3 * i + 2] - cam[2];
    float X = r00 * px + r01 * py + r02 * pz;
    float Y = r10 * px + r11 * py + r12 * pz;
    float Z = r20 * px + r21 * py + r22 * pz;
    float u = K[0] * X + K[1] * Y + K[2] * Z;
    float v = K[3] * X + K[4] * Y + K[5] * Z;
    float w = K[6] * X + K[7] * Y + K[8] * Z;
    cx[i] = u / w;
    cy[i] = v / w;
    dz[i] = Z;
    key[i] = -w;
    rank[i] = 0;          // zero-init for rank_partial's atomics (re-poison safe)
}

// Partial rank: grid (16 i-segments, 16 j-segments), 256 threads.
// Block (bi,bj) counts, for each element i in segment bi, how many keys in
// j-segment bj sort before it (stable: index tie-break). atomicAdd merges.
__global__ __launch_bounds__(256) void rank_partial_kernel(
        const float* __restrict__ keyg, int* __restrict__ rank) {
    __shared__ __align__(16) float sk[256];
    int t = threadIdx.x;
    int jbase = blockIdx.y * 256;
    sk[t] = keyg[jbase + t];
    __syncthreads();
    int i = blockIdx.x * 256 + t;
    float ki = keyg[i];
    int r = 0;
    #pragma unroll
    for (int j = 0; j < 256; j += 4) {
        float4 k4 = *reinterpret_cast<const float4*>(&sk[j]);   // LDS broadcast
        r += (k4.x < ki) || (k4.x == ki && (jbase + j + 0) < i);
        r += (k4.y < ki) || (k4.y == ki && (jbase + j + 1) < i);
        r += (k4.z < ki) || (k4.z == ki && (jbase + j + 2) < i);
        r += (k4.w < ki) || (k4.w == ki && (jbase + j + 3) < i);
    }
    if (r) atomicAdd(&rank[i], r);
}

// Scatter the sorted AoS once all partial ranks are merged.
__global__ __launch_bounds__(256) void scatter_kernel(
        const int* __restrict__ rank, const float* __restrict__ cx,
        const float* __restrict__ cy, const float* __restrict__ dz,
        const float* __restrict__ colors, const float* __restrict__ opac,
        float4* __restrict__ out) {
    int i = blockIdx.x * 256 + threadIdx.x;
    int r = rank[i];
    out[2 * r]     = make_float4(cx[i], cy[i], dz[i], opac[i]);
    out[2 * r + 1] = make_float4(colors[3 * i], colors[3 * i + 1], colors[3 * i + 2], 0.f);
}

#define CHUNK 256
#define CULL2 1444.0f   // r=38 from tile center: min pixel dist 26.7 -> skipped alpha <= 6.5e-7

__global__ __launch_bounds__(256) void render_kernel(
        const float4* __restrict__ gs, const float* __restrict__ bg,
        float* __restrict__ out) {
    __shared__ float4 cmp[2 * CHUNK];
    __shared__ unsigned long long wmask[4];
    __shared__ int walive[4];
    int tx = threadIdx.x, ty = threadIdx.y;
    int tid = ty * 16 + tx;
    int lane = tid & 63, wid = tid >> 6;
    int j = blockIdx.x * 16 + tx;
    int i = blockIdx.y * 16 + ty;
    float px = (float)j, py = (float)i;
    float tcx = blockIdx.x * 16 + 7.5f, tcy = blockIdx.y * 16 + 7.5f;
    float T = 1.f;
    float cr = bg[0], cg = bg[1], cb = bg[2];
    float da = 0.f, aa = 0.f;
    for (int c0 = 0; c0 < N_GAUSS; c0 += CHUNK) {
        // load + tile-cull test (one Gaussian per thread, order-preserving compact)
        float4 A = gs[2 * (c0 + tid)];
        float4 C = gs[2 * (c0 + tid) + 1];
        float ddx = A.x - tcx, ddy = A.y - tcy;
        bool pred = (ddx * ddx + ddy * ddy <= CULL2);
        unsigned long long m = __ballot(pred ? 1 : 0);
        unsigned long long am = __ballot(T >= 1e-6f ? 1 : 0);
        if (lane == 0) { wmask[wid] = m; walive[wid] = (am != 0ull); }
        __syncthreads();
        if (!(walive[0] | walive[1] | walive[2] | walive[3])) break;  // all pixels opaque
        unsigned long long m0 = wmask[0], m1 = wmask[1], m2 = wmask[2], m3 = wmask[3];
        int total = __popcll(m0) + __popcll(m1) + __popcll(m2) + __popcll(m3);
        if (pred) {
            int base = 0;
            if (wid > 0) base += __popcll(m0);
            if (wid > 1) base += __popcll(m1);
            if (wid > 2) base += __popcll(m2);
            int pos = base + __popcll(m & ((1ull << lane) - 1ull));
            cmp[2 * pos]     = A;
            cmp[2 * pos + 1] = C;
        }
        __syncthreads();
        for (int g = 0; g < total; ++g) {
            float4 GA = cmp[2 * g];                     // LDS broadcast
            float dx = px - GA.x, dy = py - GA.y;
            float al = __expf(-0.02f * (dx * dx + dy * dy)) * GA.w;  // op<=0.5 -> clip is no-op
            float ta = T * al;
            float4 GC = cmp[2 * g + 1];
            cr += ta * GC.x; cg += ta * GC.y; cb += ta * GC.z;
            da += ta * GA.z; aa += ta;
            T -= ta;                                    // T *= (1-al)
        }
        __syncthreads();
    }
    int pid = i * W + j;
    out[pid]          = cr;
    out[HW + pid]     = cg;
    out[2 * HW + pid] = cb;
    out[3 * HW + pid] = da;
    out[4 * HW + pid] = aa;
}

extern "C" void kernel_launch(void* const* d_in, const int* in_sizes, int n_in,
                              void* d_out, int out_size, void* d_ws, size_t ws_size,
                              hipStream_t stream) {
    const float* positions = (const float*)d_in[0];
    const float* colors    = (const float*)d_in[1];
    const float* opacities = (const float*)d_in[2];
    const float* quat      = (const float*)d_in[3];
    const float* cam       = (const float*)d_in[4];
    const float* intr      = (const float*)d_in[5];
    const float* bg        = (const float*)d_in[6];
    float* out = (float*)d_out;

    float* ws  = (float*)d_ws;
    float* cx  = ws;
    float* cy  = ws + 4096;
    float* dz  = ws + 8192;
    float* key = ws + 12288;
    int*   rank = (int*)(ws + 16384);
    float4* sorted = (float4*)(ws + 20480);

    proj_kernel<<<dim3(N_GAUSS / 256), dim3(256), 0, stream>>>(
        positions, quat, cam, intr, cx, cy, dz, key, rank);
    rank_partial_kernel<<<dim3(16, 16), dim3(256), 0, stream>>>(key, rank);
    scatter_kernel<<<dim3(N_GAUSS / 256), dim3(256), 0, stream>>>(
        rank, cx, cy, dz, colors, opacities, sorted);
    render_kernel<<<dim3(W / 16, H / 16), dim3(16, 16), 0, stream>>>(
        sorted, bg, out);
}